// Round 6
// baseline (314.274 us; speedup 1.0000x reference)
//
#include <hip/hip_runtime.h>

// ---------------------------------------------------------------------------
// GCN block: 3x (MFMA bf16 GEMM -> degree-normalized aggregate), resid, relu.
// 9 dispatches: memset(cursors) | scatter(fixed-CAP buckets) |
//   sort(+dinv,+rp2) | gemm1 | agg1 | gemm2 | agg2 | gemm3 | agg3
// R18: XCD-SHARDED FEATURE-SPLIT AGG. R16/R17 proved agg is bound by random
// L2-miss line transactions (hs 12.8MB > 4MB XCD L2, ~53% hit; widening and
// col pipelining both null). hs/xtb/hb now stored as 4 sub-tables
// [4][N+1][16] bf16 (3.2MB each, L2-resident). One agg dispatch; pass =
// bid&3 aligns with round-robin bid->XCD so each XCD gathers only from ITS
// sub-table (perf heuristic only; correctness independent of mapping).
// Wave = 4 nodes x 4 edge-slots x 4 feats: 16 edges/gather-inst; masked
// 8-edge strided loop (PADS=0, no col padding) with depth-2 col prefetch and
// 2 gathers in flight. GEMM epilogues write split layout; gemm64 A-load
// reads split layout (better coalesced: 32B row stride vs 128B).
// R16: single-pass scatter; bucketed sort keeps col writes L2-local (R15:
// direct fill = 104MB write amplification). R9: dinv in GEMM epilogue.
// ---------------------------------------------------------------------------

#define LB 8
#define BKN 256
#define CHUNK 4096
#define EPT 16                     // edges per thread in scatter (CHUNK/256)
#define CAP 8192                   // packed slots per bucket (mean fill 4092)

typedef unsigned short ushort_t;
typedef __attribute__((ext_vector_type(8))) short bf16x8;
typedef __attribute__((ext_vector_type(4))) float f32x4;

__device__ __forceinline__ unsigned f2bf(float f) {
    unsigned u = __builtin_bit_cast(unsigned, f);
    return (u + 0x7FFFu + ((u >> 16) & 1u)) >> 16;   // RNE
}
__device__ __forceinline__ float bf2f(ushort_t h) {
    unsigned u = ((unsigned)h) << 16;
    return __builtin_bit_cast(float, u);
}
__device__ __forceinline__ float bflo(unsigned u) {
    return __builtin_bit_cast(float, u << 16);
}
__device__ __forceinline__ float bfhi(unsigned u) {
    return __builtin_bit_cast(float, u & 0xFFFF0000u);
}

// per-block int64-vs-int32 probe (sampled; same result in every block)
__device__ int detect_f64(const int* ei, int E, int* sflag) {
    if (threadIdx.x == 0) *sflag = 0;
    __syncthreads();
    const unsigned* raw = (const unsigned*)ei;
    int dwords = min(2 * E, 512);
    int any = 0;
    for (int i = threadIdx.x; i < dwords; i += blockDim.x)
        if ((i & 1) && raw[i]) any = 1;
    if (any) atomicOr(sflag, 1);
    __syncthreads();
    return !*sflag;   // all sampled high words zero => int64
}

// ---- scatter: partition edges into fixed-CAP bucket regions ---------------
// packed[b*CAP + cursor] = (src<<8 | dst&255); cursor is RELATIVE (0-init).
// Single pass over ei: each thread keeps its EPT edges in (unrolled) regs.
__global__ __launch_bounds__(256) void k_scatter(
        const int* __restrict__ ei, int E,
        int* __restrict__ bucketCursor, unsigned int* __restrict__ packed) {
    __shared__ int hist[512];
    __shared__ int base[512];
    __shared__ int sflag;
    int f64 = detect_f64(ei, E, &sflag);
    int b0 = blockIdx.x * CHUNK;
    int n = min(CHUNK, E - b0);
    int tid = threadIdx.x;
    for (int i = tid; i < 512; i += 256) hist[i] = 0;
    __syncthreads();
    int dreg[EPT], sreg[EPT];
#pragma unroll
    for (int i = 0; i < EPT; i++) {
        int idx = tid + i * 256;
        if (idx < n) {
            int e = b0 + idx;
            dreg[i] = f64 ? ei[2 * (E + e)] : ei[E + e];
            sreg[i] = f64 ? ei[2 * e] : ei[e];
            atomicAdd(&hist[dreg[i] >> LB], 1);
        }
    }
    __syncthreads();
    for (int i = tid; i < 512; i += 256) {
        int c = hist[i];
        base[i] = c ? atomicAdd(&bucketCursor[i], c) : 0;
        hist[i] = 0;
    }
    __syncthreads();
#pragma unroll
    for (int i = 0; i < EPT; i++) {
        int idx = tid + i * 256;
        if (idx < n) {
            int bk = dreg[i] >> LB;
            int pos = bk * CAP + base[bk] + atomicAdd(&hist[bk], 1);
            packed[pos] = ((unsigned)sreg[i] << LB) | (unsigned)(dreg[i] & (BKN - 1));
        }
    }
}

// ---- per-bucket counting sort -> exact CSR col[], rp2, dinv ---------------
// Bucket b's packed region: [b*CAP, b*CAP + cnt) with cnt = bucketCursor[b].
// No padding (agg masks per-lane). Sentinel row N of each of the 4 hs
// sub-tables zeroed here. col scatter stays within a 32KB L2-local region.
__global__ __launch_bounds__(256) void k_sort(
        const unsigned int* __restrict__ packed, const int* __restrict__ bucketCursor,
        int* __restrict__ col, int2* __restrict__ rp2, float* __restrict__ dinv,
        ushort_t* __restrict__ hs, int N) {
    __shared__ int hist[BKN];
    __shared__ int s[BKN];
    __shared__ int cur[BKN];
    int tid = threadIdx.x;
    int b = blockIdx.x;
    int start = b * CAP;
    int end = start + bucketCursor[b];
    hist[tid] = 0;
    __syncthreads();
    for (int e = start + tid; e < end; e += 256)
        atomicAdd(&hist[packed[e] & (BKN - 1)], 1);
    __syncthreads();
    int v = hist[tid];
    s[tid] = v;
    __syncthreads();
    for (int off = 1; off < 256; off <<= 1) {
        int x = (tid >= off) ? s[tid - off] : 0;
        __syncthreads();
        if (tid >= off) s[tid] += x;
        __syncthreads();
    }
    int st = b * CAP + s[tid] - v;      // exact prefix, buckets disjoint
    cur[tid] = st;
    int node = (b << LB) + tid;
    if (node < N) {
        rp2[node] = make_int2(st, st + v);
        dinv[node] = rsqrtf((float)(v + 1));   // +1 self loop
    }
    // zero sentinel row N of each sub-table: hs[sub][N][0..15]
    if (b == 0 && tid < 64) {
        size_t ns = (size_t)N + 1;
        hs[((size_t)(tid >> 4) * ns + N) * 16 + (tid & 15)] = 0;
    }
    __syncthreads();
    for (int e = start + tid; e < end; e += 256) {
        unsigned pvk = packed[e];
        int pos = atomicAdd(&cur[pvk & (BKN - 1)], 1);
        col[pos] = (int)(pvk >> LB);
    }
}

// ---- gemm1: (N x 128) @ (128 x 64), f32 in, dinv-scaled, split bf16 out ---
__global__ __launch_bounds__(256) void k_gemm1(
        const float* __restrict__ A, const float* __restrict__ W,
        const float* __restrict__ dinv, ushort_t* __restrict__ out, int nrows) {
    const int K = 128;
    size_t ns = (size_t)nrows + 1;
    __shared__ ushort_t sWT[64 * (K + 8)];
    int tid = threadIdx.x;
    for (int i = tid; i < K * 64; i += 256) {
        int n = i & 63, k = i >> 6;
        sWT[n * (K + 8) + k] = (ushort_t)f2bf(W[i]);
    }
    __syncthreads();
    int wave = tid >> 6, lane = tid & 63;
    int quad = lane >> 4, l16 = lane & 15;
    int rowBase = blockIdx.x * 128 + wave * 32;
    f32x4 acc[2][4];
#pragma unroll
    for (int r = 0; r < 2; r++)
#pragma unroll
        for (int c = 0; c < 4; c++) acc[r][c] = (f32x4){0.f, 0.f, 0.f, 0.f};
#pragma unroll
    for (int chunk = 0; chunk < K / 32; chunk++) {
        bf16x8 afr[2];
#pragma unroll
        for (int r = 0; r < 2; r++) {
            int row = rowBase + r * 16 + l16;
            if (row >= nrows) row = nrows - 1;
            const float* ap = A + (size_t)row * K + chunk * 32 + quad * 8;
            float4 v0 = *(const float4*)ap;
            float4 v1 = *(const float4*)(ap + 4);
            bf16x8 a;
            a[0] = (short)f2bf(v0.x); a[1] = (short)f2bf(v0.y);
            a[2] = (short)f2bf(v0.z); a[3] = (short)f2bf(v0.w);
            a[4] = (short)f2bf(v1.x); a[5] = (short)f2bf(v1.y);
            a[6] = (short)f2bf(v1.z); a[7] = (short)f2bf(v1.w);
            afr[r] = a;
        }
#pragma unroll
        for (int c = 0; c < 4; c++) {
            bf16x8 bfr = __builtin_bit_cast(
                bf16x8,
                *(const uint4*)&sWT[(c * 16 + l16) * (K + 8) + chunk * 32 + quad * 8]);
#pragma unroll
            for (int r = 0; r < 2; r++)
                acc[r][c] = __builtin_amdgcn_mfma_f32_16x16x32_bf16(
                    afr[r], bfr, acc[r][c], 0, 0, 0);
        }
    }
#pragma unroll
    for (int r = 0; r < 2; r++)
#pragma unroll
        for (int i = 0; i < 4; i++) {
            int row = rowBase + r * 16 + quad * 4 + i;
            if (row < nrows) {
                float sc = dinv[row];
#pragma unroll
                for (int c = 0; c < 4; c++)
                    out[((size_t)c * ns + row) * 16 + l16] =
                        (ushort_t)f2bf(acc[r][c][i] * sc);
            }
        }
}

// ---- gemm64: (N x 64) @ (64 x 64), split bf16 in/out, dinv-scaled ---------
__global__ __launch_bounds__(256) void k_gemm64(
        const ushort_t* __restrict__ A, const float* __restrict__ W,
        const float* __restrict__ dinv, ushort_t* __restrict__ out, int nrows) {
    const int K = 64;
    size_t ns = (size_t)nrows + 1;
    __shared__ ushort_t sWT[64 * (K + 8)];
    int tid = threadIdx.x;
    for (int i = tid; i < K * 64; i += 256) {
        int n = i & 63, k = i >> 6;
        sWT[n * (K + 8) + k] = (ushort_t)f2bf(W[i]);
    }
    __syncthreads();
    int wave = tid >> 6, lane = tid & 63;
    int quad = lane >> 4, l16 = lane & 15;
    int rowBase = blockIdx.x * 128 + wave * 32;
    f32x4 acc[2][4];
#pragma unroll
    for (int r = 0; r < 2; r++)
#pragma unroll
        for (int c = 0; c < 4; c++) acc[r][c] = (f32x4){0.f, 0.f, 0.f, 0.f};
#pragma unroll
    for (int chunk = 0; chunk < K / 32; chunk++) {
        bf16x8 afr[2];
        int sub = chunk * 2 + (quad >> 1);
        int off = (quad & 1) * 8;
#pragma unroll
        for (int r = 0; r < 2; r++) {
            int row = rowBase + r * 16 + l16;
            if (row >= nrows) row = nrows - 1;
            const ushort_t* ap = A + ((size_t)sub * ns + row) * 16 + off;
            afr[r] = __builtin_bit_cast(bf16x8, *(const uint4*)ap);
        }
#pragma unroll
        for (int c = 0; c < 4; c++) {
            bf16x8 bfr = __builtin_bit_cast(
                bf16x8,
                *(const uint4*)&sWT[(c * 16 + l16) * (K + 8) + chunk * 32 + quad * 8]);
#pragma unroll
            for (int r = 0; r < 2; r++)
                acc[r][c] = __builtin_amdgcn_mfma_f32_16x16x32_bf16(
                    afr[r], bfr, acc[r][c], 0, 0, 0);
        }
    }
#pragma unroll
    for (int r = 0; r < 2; r++)
#pragma unroll
        for (int i = 0; i < 4; i++) {
            int row = rowBase + r * 16 + quad * 4 + i;
            if (row < nrows) {
                float sc = dinv[row];
#pragma unroll
                for (int c = 0; c < 4; c++)
                    out[((size_t)c * ns + row) * 16 + l16] =
                        (ushort_t)f2bf(acc[r][c][i] * sc);
            }
        }
}

// ---- aggregation: pass-sharded. 4 nodes/wave, 16 edges/gather-inst --------
// pass f = bid&3 selects 16-feature sub-table (3.2MB, XCD-L2-resident under
// round-robin bid->XCD). Lane = nl(2b) | g(2b) | c(2b): node-slot, edge-slot,
// feature-quad. One gather inst covers 4 nodes x 4 edges; loop advances 8
// edges/node/iter (2 gathers + 2 col loads in flight, depth-2 col prefetch).
// Out-of-range slots masked to sentinel row N (zeros, L1-hot). Reduce over g
// = shfl_xor(4,8); lanes g==0 write.
template <int RELU, int F32OUT>
__global__ __launch_bounds__(256) void k_agg16(
        const ushort_t* __restrict__ hs, const float* __restrict__ dinv,
        const float* __restrict__ bias, const int* __restrict__ col,
        const int2* __restrict__ rp2, const ushort_t* __restrict__ residb,
        float* __restrict__ outf, ushort_t* __restrict__ outb, int n) {
    size_t ns = (size_t)n + 1;
    int bid = blockIdx.x;
    int f = bid & 3;
    int wid = threadIdx.x >> 6;
    int lane = threadIdx.x & 63;
    int nl = lane >> 4;                  // node slot 0..3
    int g = (lane >> 2) & 3;             // edge slot 0..3
    int c = lane & 3;                    // feature quad: feats c*4..c*4+3
    int node = (bid >> 2) * 16 + wid * 4 + nl;
    const ushort_t* sub = hs + (size_t)f * ns * 16;

    int2 r = rp2[node < n ? node : n - 1];
    int e = r.x, p = r.y;
    if (node >= n) { e = 0; p = 0; }
    uint2 us = *(const uint2*)(sub + (size_t)(node < n ? node : 0) * 16 + c * 4);
    float a0 = 0.f, a1 = 0.f, a2 = 0.f, a3 = 0.f;

#define GR(m) (*(const uint2*)(sub + (size_t)(m) * 16 + c * 4))
#define GACC(u)                                                             \
    a0 += bflo(u.x); a1 += bfhi(u.x);                                       \
    a2 += bflo(u.y); a3 += bfhi(u.y);

    bool any = __any(e < p);
    int cv0 = 0, cv1 = 0;
    if (any) { cv0 = col[e + g]; cv1 = col[e + 4 + g]; }
    while (any) {
        int m0 = (e + g < p) ? cv0 : n;      // masked slots -> sentinel row
        int m1 = (e + 4 + g < p) ? cv1 : n;
        uint2 u0 = GR(m0);
        uint2 u1 = GR(m1);
        e += 8;
        any = __any(e < p);
        if (any) { cv0 = col[e + g]; cv1 = col[e + 4 + g]; }
        GACC(u0) GACC(u1)
    }
#undef GR
#undef GACC

    a0 += __shfl_xor(a0, 4); a0 += __shfl_xor(a0, 8);
    a1 += __shfl_xor(a1, 4); a1 += __shfl_xor(a1, 8);
    a2 += __shfl_xor(a2, 4); a2 += __shfl_xor(a2, 8);
    a3 += __shfl_xor(a3, 4); a3 += __shfl_xor(a3, 8);

    if (g == 0 && node < n) {
        a0 += bflo(us.x); a1 += bfhi(us.x);
        a2 += bflo(us.y); a3 += bfhi(us.y);
        float sc = dinv[node];
        float4 bv = *(const float4*)(bias + f * 16 + c * 4);
        float o0 = sc * a0 + bv.x, o1 = sc * a1 + bv.y;
        float o2 = sc * a2 + bv.z, o3 = sc * a3 + bv.w;
        if (RELU) {
            o0 = fmaxf(o0, 0.f); o1 = fmaxf(o1, 0.f);
            o2 = fmaxf(o2, 0.f); o3 = fmaxf(o3, 0.f);
        }
        if (F32OUT) {
            uint2 rb = *(const uint2*)(residb + ((size_t)f * ns + node) * 16 + c * 4);
            o0 += bflo(rb.x); o1 += bfhi(rb.x);
            o2 += bflo(rb.y); o3 += bfhi(rb.y);
            *(float4*)(outf + (size_t)node * 64 + f * 16 + c * 4) =
                make_float4(o0, o1, o2, o3);
        } else {
            unsigned w0 = f2bf(o0) | (f2bf(o1) << 16);
            unsigned w1 = f2bf(o2) | (f2bf(o3) << 16);
            *(uint2*)(outb + ((size_t)f * ns + node) * 16 + c * 4) =
                make_uint2(w0, w1);
        }
    }
}

// ---------------------------------------------------------------------------
extern "C" void kernel_launch(void* const* d_in, const int* in_sizes, int n_in,
                              void* d_out, int out_size, void* d_ws, size_t ws_size,
                              hipStream_t stream) {
    const float* x  = (const float*)d_in[0];
    const int*   ei = (const int*)d_in[1];
    const float* W0 = (const float*)d_in[2];
    const float* b0 = (const float*)d_in[3];
    const float* Ws = (const float*)d_in[4];
    const float* bs = (const float*)d_in[5];
    float* out = (float*)d_out;

    const int N = in_sizes[0] / 128;
    const int E = in_sizes[1] / 2;
    const int B = (N + BKN - 1) >> LB;

    char* p = (char*)d_ws;
    auto carve = [&](size_t bytes) {
        char* r = p;
        p += (bytes + 255) & ~(size_t)255;
        return r;
    };
    int*      bucketCursor = (int*)carve(512 * 4);
    unsigned* packed       = (unsigned*)carve((size_t)B * CAP * 4);
    int*      col          = (int*)carve(((size_t)B * CAP + 128) * 4);  // +guard
    int2*     rp2          = (int2*)carve((size_t)N * 8);
    float*    dinv         = (float*)carve((size_t)N * 4);
    ushort_t* hs           = (ushort_t*)carve((size_t)(N + 1) * 64 * 2); // split+sent
    ushort_t* xtb          = (ushort_t*)carve((size_t)(N + 1) * 64 * 2);
    ushort_t* hb           = (ushort_t*)carve((size_t)(N + 1) * 64 * 2);

    hipMemsetAsync(bucketCursor, 0, 512 * 4, stream);

    k_scatter<<<(E + CHUNK - 1) / CHUNK, 256, 0, stream>>>(ei, E, bucketCursor, packed);
    k_sort<<<B, 256, 0, stream>>>(packed, bucketCursor, col, rp2, dinv, hs, N);

    int gb = (N + 127) / 128;
    int ablocks = ((N + 15) / 16) * 4;   // 4 nodes/wave, 4 waves/block, x4 passes

    // layer 1: hs = split(x @ W0)*dinv ; agg1 -> xtb (split bf16, +b0)
    k_gemm1<<<gb, 256, 0, stream>>>(x, W0, dinv, hs, N);
    k_agg16<0, 0><<<ablocks, 256, 0, stream>>>(hs, dinv, b0, col, rp2,
                                               nullptr, nullptr, xtb, N);
    // layer 2: hs = split(xtb @ Ws0)*dinv ; agg2 -> hb (split bf16, +bs0, relu)
    k_gemm64<<<gb, 256, 0, stream>>>(xtb, Ws, dinv, hs, N);
    k_agg16<1, 0><<<ablocks, 256, 0, stream>>>(hs, dinv, bs, col, rp2,
                                               nullptr, nullptr, hb, N);
    // layer 3: hs = split(hb @ Ws1)*dinv ; agg3 -> out (f32, +bs1, relu, +resid)
    k_gemm64<<<gb, 256, 0, stream>>>(hb, Ws + 64 * 64, dinv, hs, N);
    k_agg16<1, 1><<<ablocks, 256, 0, stream>>>(hs, dinv, bs + 64, col, rp2,
                                               xtb, out, nullptr, N);
}

// Round 7
// 288.128 us; speedup vs baseline: 1.0907x; 1.0907x over previous
//
#include <hip/hip_runtime.h>

// ---------------------------------------------------------------------------
// GCN block: 3x (MFMA bf16 GEMM -> degree-normalized aggregate), resid, relu.
// 9 dispatches: memset(cursors) | scatter(fixed-CAP buckets) |
//   sort(+pad,+dinv,+rp2) | gemm1 | agg1 | gemm2 | agg2 | gemm3 | agg3
// R19: agg restructured ISSUE-ALL-THEN-ACCUMULATE. Evidence (R16-R18): agg
// time invariant under col pipelining, VMEM width, and HBM traffic (R18 cut
// FETCH 95->59MB yet time rose) => per-wave serialized latency chains, not
// bandwidth. New walk: wave-uniform tiers by degree -- <=16: batch 4 col +
// 4 gathers, ONE wait, accumulate; 17..32 (43% of nodes): batch 8+8; >32
// (P~2e-4): rare 32-burst loop then masked tail. Out-of-segment slots mask
// to sentinel row N (L1-hot). rp2/self/dinv issued up-front in parallel.
// Chain/wave ~ rp2+col+gather (~2.1K cyc) vs ~4.5K before.
// R18 lesson: XCD shard cut FETCH but 4x pass overhead cost more -- agg is
// NOT fill-BW bound. R16: single-pass scatter; bucketed sort keeps col
// writes L2-local (R15: direct fill = 104MB write amplification).
// R14: direct col loads. R13: 1 node/wave, uint2 16-lanes/row.
// R10 lesson: no barrier-coupled gather fusion. R9: dinv in GEMM epilogue.
// ---------------------------------------------------------------------------

#define LB 8
#define BKN 256
#define CHUNK 4096
#define EPT 16                     // edges per thread in scatter (CHUNK/256)
#define CAP 8192                   // packed slots per bucket (mean fill 4092)
#define PADS 3                     // segment padding to x4
#define CAPCOL (CAP + BKN * PADS)  // padded col region per bucket

typedef unsigned short ushort_t;
typedef __attribute__((ext_vector_type(8))) short bf16x8;
typedef __attribute__((ext_vector_type(4))) float f32x4;

__device__ __forceinline__ unsigned f2bf(float f) {
    unsigned u = __builtin_bit_cast(unsigned, f);
    return (u + 0x7FFFu + ((u >> 16) & 1u)) >> 16;   // RNE
}
__device__ __forceinline__ float bf2f(ushort_t h) {
    unsigned u = ((unsigned)h) << 16;
    return __builtin_bit_cast(float, u);
}
__device__ __forceinline__ float bflo(unsigned u) {
    return __builtin_bit_cast(float, u << 16);
}
__device__ __forceinline__ float bfhi(unsigned u) {
    return __builtin_bit_cast(float, u & 0xFFFF0000u);
}

// per-block int64-vs-int32 probe (sampled; same result in every block)
__device__ int detect_f64(const int* ei, int E, int* sflag) {
    if (threadIdx.x == 0) *sflag = 0;
    __syncthreads();
    const unsigned* raw = (const unsigned*)ei;
    int dwords = min(2 * E, 512);
    int any = 0;
    for (int i = threadIdx.x; i < dwords; i += blockDim.x)
        if ((i & 1) && raw[i]) any = 1;
    if (any) atomicOr(sflag, 1);
    __syncthreads();
    return !*sflag;   // all sampled high words zero => int64
}

// ---- scatter: partition edges into fixed-CAP bucket regions ---------------
// packed[b*CAP + cursor] = (src<<8 | dst&255); cursor is RELATIVE (0-init).
// Single pass over ei: each thread keeps its EPT edges in (unrolled) regs.
__global__ __launch_bounds__(256) void k_scatter(
        const int* __restrict__ ei, int E,
        int* __restrict__ bucketCursor, unsigned int* __restrict__ packed) {
    __shared__ int hist[512];
    __shared__ int base[512];
    __shared__ int sflag;
    int f64 = detect_f64(ei, E, &sflag);
    int b0 = blockIdx.x * CHUNK;
    int n = min(CHUNK, E - b0);
    int tid = threadIdx.x;
    for (int i = tid; i < 512; i += 256) hist[i] = 0;
    __syncthreads();
    int dreg[EPT], sreg[EPT];
#pragma unroll
    for (int i = 0; i < EPT; i++) {
        int idx = tid + i * 256;
        if (idx < n) {
            int e = b0 + idx;
            dreg[i] = f64 ? ei[2 * (E + e)] : ei[E + e];
            sreg[i] = f64 ? ei[2 * e] : ei[e];
            atomicAdd(&hist[dreg[i] >> LB], 1);
        }
    }
    __syncthreads();
    for (int i = tid; i < 512; i += 256) {
        int c = hist[i];
        base[i] = c ? atomicAdd(&bucketCursor[i], c) : 0;
        hist[i] = 0;
    }
    __syncthreads();
#pragma unroll
    for (int i = 0; i < EPT; i++) {
        int idx = tid + i * 256;
        if (idx < n) {
            int bk = dreg[i] >> LB;
            int pos = bk * CAP + base[bk] + atomicAdd(&hist[bk], 1);
            packed[pos] = ((unsigned)sreg[i] << LB) | (unsigned)(dreg[i] & (BKN - 1));
        }
    }
}

// ---- per-bucket counting sort -> padded CSR col[], rp2, dinv --------------
// Bucket b's packed region: [b*CAP, b*CAP + cnt) with cnt = bucketCursor[b].
// Node segments padded to x4 with sentinel index N; hs row N zeroed here.
// col scatter-writes land within this bucket's 36KB CAPCOL region (L2-local).
__global__ __launch_bounds__(256) void k_sort(
        const unsigned int* __restrict__ packed, const int* __restrict__ bucketCursor,
        int* __restrict__ col, int2* __restrict__ rp2, float* __restrict__ dinv,
        ushort_t* __restrict__ hs, int N) {
    __shared__ int hist[BKN];
    __shared__ int s[BKN];
    __shared__ int cur[BKN];
    int tid = threadIdx.x;
    int b = blockIdx.x;
    int start = b * CAP;
    int end = start + bucketCursor[b];
    hist[tid] = 0;
    __syncthreads();
    for (int e = start + tid; e < end; e += 256)
        atomicAdd(&hist[packed[e] & (BKN - 1)], 1);
    __syncthreads();
    int v = hist[tid];
    int pv = (v + PADS) & ~PADS;        // padded length (x4)
    s[tid] = pv;
    __syncthreads();
    for (int off = 1; off < 256; off <<= 1) {
        int x = (tid >= off) ? s[tid - off] : 0;
        __syncthreads();
        if (tid >= off) s[tid] += x;
        __syncthreads();
    }
    int excl = s[tid] - pv;
    int st = b * CAPCOL + excl;         // padded col base, buckets disjoint
    cur[tid] = st;
    int node = (b << LB) + tid;
    if (node < N) {
        rp2[node] = make_int2(st, st + pv);
        dinv[node] = rsqrtf((float)(v + 1));   // +1 self loop
        for (int i = v; i < pv; i++) col[st + i] = N;   // sentinel padding
    }
    if (b == 0 && tid < 64) hs[(size_t)N * 64 + tid] = 0;   // zero row N
    __syncthreads();
    for (int e = start + tid; e < end; e += 256) {
        unsigned pvk = packed[e];
        int pos = atomicAdd(&cur[pvk & (BKN - 1)], 1);
        col[pos] = (int)(pvk >> LB);
    }
}

// ---- gemm1: (N x 128) @ (128 x 64), f32 in, dinv-scaled, bf16 out ---------
__global__ __launch_bounds__(256) void k_gemm1(
        const float* __restrict__ A, const float* __restrict__ W,
        const float* __restrict__ dinv, ushort_t* __restrict__ out, int nrows) {
    const int K = 128;
    __shared__ ushort_t sWT[64 * (K + 8)];
    int tid = threadIdx.x;
    for (int i = tid; i < K * 64; i += 256) {
        int n = i & 63, k = i >> 6;
        sWT[n * (K + 8) + k] = (ushort_t)f2bf(W[i]);
    }
    __syncthreads();
    int wave = tid >> 6, lane = tid & 63;
    int quad = lane >> 4, l16 = lane & 15;
    int rowBase = blockIdx.x * 128 + wave * 32;
    f32x4 acc[2][4];
#pragma unroll
    for (int r = 0; r < 2; r++)
#pragma unroll
        for (int c = 0; c < 4; c++) acc[r][c] = (f32x4){0.f, 0.f, 0.f, 0.f};
#pragma unroll
    for (int chunk = 0; chunk < K / 32; chunk++) {
        bf16x8 afr[2];
#pragma unroll
        for (int r = 0; r < 2; r++) {
            int row = rowBase + r * 16 + l16;
            if (row >= nrows) row = nrows - 1;
            const float* ap = A + (size_t)row * K + chunk * 32 + quad * 8;
            float4 v0 = *(const float4*)ap;
            float4 v1 = *(const float4*)(ap + 4);
            bf16x8 a;
            a[0] = (short)f2bf(v0.x); a[1] = (short)f2bf(v0.y);
            a[2] = (short)f2bf(v0.z); a[3] = (short)f2bf(v0.w);
            a[4] = (short)f2bf(v1.x); a[5] = (short)f2bf(v1.y);
            a[6] = (short)f2bf(v1.z); a[7] = (short)f2bf(v1.w);
            afr[r] = a;
        }
#pragma unroll
        for (int c = 0; c < 4; c++) {
            bf16x8 bfr = __builtin_bit_cast(
                bf16x8,
                *(const uint4*)&sWT[(c * 16 + l16) * (K + 8) + chunk * 32 + quad * 8]);
#pragma unroll
            for (int r = 0; r < 2; r++)
                acc[r][c] = __builtin_amdgcn_mfma_f32_16x16x32_bf16(
                    afr[r], bfr, acc[r][c], 0, 0, 0);
        }
    }
#pragma unroll
    for (int r = 0; r < 2; r++)
#pragma unroll
        for (int i = 0; i < 4; i++) {
            int row = rowBase + r * 16 + quad * 4 + i;
            if (row < nrows) {
                float sc = dinv[row];
#pragma unroll
                for (int c = 0; c < 4; c++)
                    out[(size_t)row * 64 + c * 16 + l16] =
                        (ushort_t)f2bf(acc[r][c][i] * sc);
            }
        }
}

// ---- gemm64: (N x 64) @ (64 x 64), bf16 in, dinv-scaled, bf16 out ---------
__global__ __launch_bounds__(256) void k_gemm64(
        const ushort_t* __restrict__ A, const float* __restrict__ W,
        const float* __restrict__ dinv, ushort_t* __restrict__ out, int nrows) {
    const int K = 64;
    __shared__ ushort_t sWT[64 * (K + 8)];
    int tid = threadIdx.x;
    for (int i = tid; i < K * 64; i += 256) {
        int n = i & 63, k = i >> 6;
        sWT[n * (K + 8) + k] = (ushort_t)f2bf(W[i]);
    }
    __syncthreads();
    int wave = tid >> 6, lane = tid & 63;
    int quad = lane >> 4, l16 = lane & 15;
    int rowBase = blockIdx.x * 128 + wave * 32;
    f32x4 acc[2][4];
#pragma unroll
    for (int r = 0; r < 2; r++)
#pragma unroll
        for (int c = 0; c < 4; c++) acc[r][c] = (f32x4){0.f, 0.f, 0.f, 0.f};
#pragma unroll
    for (int chunk = 0; chunk < K / 32; chunk++) {
        bf16x8 afr[2];
#pragma unroll
        for (int r = 0; r < 2; r++) {
            int row = rowBase + r * 16 + l16;
            if (row >= nrows) row = nrows - 1;
            const ushort_t* ap = A + (size_t)row * K + chunk * 32 + quad * 8;
            afr[r] = __builtin_bit_cast(bf16x8, *(const uint4*)ap);
        }
#pragma unroll
        for (int c = 0; c < 4; c++) {
            bf16x8 bfr = __builtin_bit_cast(
                bf16x8,
                *(const uint4*)&sWT[(c * 16 + l16) * (K + 8) + chunk * 32 + quad * 8]);
#pragma unroll
            for (int r = 0; r < 2; r++)
                acc[r][c] = __builtin_amdgcn_mfma_f32_16x16x32_bf16(
                    afr[r], bfr, acc[r][c], 0, 0, 0);
        }
    }
#pragma unroll
    for (int r = 0; r < 2; r++)
#pragma unroll
        for (int i = 0; i < 4; i++) {
            int row = rowBase + r * 16 + quad * 4 + i;
            if (row < nrows) {
                float sc = dinv[row];
#pragma unroll
                for (int c = 0; c < 4; c++)
                    out[(size_t)row * 64 + c * 16 + l16] =
                        (ushort_t)f2bf(acc[r][c][i] * sc);
            }
        }
}

// ---- aggregation: ONE node per wave, issue-all-then-accumulate ------------
// Row = 64 bf16 = 128B = 16 lanes x uint2. Lane group g = lane>>4 owns edge
// slot 4t+g. Wave-uniform degree tiers: pv<=16 -> 4 col + 4 gathers batched,
// single wait, accumulate; pv<=32 -> 8+8 batched; pv>32 (P~2e-4) -> unmasked
// 32-bursts then masked tail. Slots >= pv map to sentinel row N (zeros,
// L1-hot); col overreads stay inside the +guard region. rp2/self/dinv issue
// up-front in parallel. Cross-group reduce shfl_xor(16/32); lanes 0-15 write.
template <int RELU, int F32OUT>
__global__ __launch_bounds__(256) void k_aggb(
        const ushort_t* __restrict__ hs, const float* __restrict__ dinv,
        const float* __restrict__ bias, const int* __restrict__ col,
        const int2* __restrict__ rp2, const ushort_t* __restrict__ residb,
        float* __restrict__ outf, ushort_t* __restrict__ outb, int n) {
    int node = (int)((blockIdx.x * blockDim.x + threadIdx.x) >> 6);
    if (node >= n) return;
    int lane = threadIdx.x & 63;
    int g = lane >> 4;                   // edge sub-slot within a 16-batch
    int c4 = lane & 15;                  // feature group: cols c4*4..c4*4+3
    const ushort_t* hrow = hs + (size_t)c4 * 4;
    // independent loads first: self row, dinv, then rp2 (all in flight)
    uint2 us = *(const uint2*)(hs + (size_t)node * 64 + c4 * 4);  // self loop
    float sc = dinv[node];
    int2 r = rp2[node];
    int e = r.x, p = r.y;                // p-e multiple of 4
    float a0 = 0.f, a1 = 0.f, a2 = 0.f, a3 = 0.f;

#define GR(m) (*(const uint2*)(hrow + (size_t)(m) * 64))
#define GACC(u)                                                             \
    a0 += bflo(u.x); a1 += bfhi(u.x);                                       \
    a2 += bflo(u.y); a3 += bfhi(u.y);

    while (p - e > 32) {                 // rare (P(deg>32) ~ 2e-4)
        int m0 = col[e + g],      m1 = col[e + 4 + g];
        int m2 = col[e + 8 + g],  m3 = col[e + 12 + g];
        int m4 = col[e + 16 + g], m5 = col[e + 20 + g];
        int m6 = col[e + 24 + g], m7 = col[e + 28 + g];
        uint2 u0 = GR(m0), u1 = GR(m1), u2 = GR(m2), u3 = GR(m3);
        uint2 u4 = GR(m4), u5 = GR(m5), u6 = GR(m6), u7 = GR(m7);
        GACC(u0) GACC(u1) GACC(u2) GACC(u3)
        GACC(u4) GACC(u5) GACC(u6) GACC(u7)
        e += 32;
    }
    int rem = p - e;                     // 0..32, multiple of 4
    if (rem > 16) {
        // slots 0..15 all valid (rem >= 20); slots 16..31 masked
        int c0 = col[e + g],      c1 = col[e + 4 + g];
        int c2 = col[e + 8 + g],  c3 = col[e + 12 + g];
        int c5 = col[e + 16 + g], c6 = col[e + 20 + g];
        int c7 = col[e + 24 + g], c8 = col[e + 28 + g];
        int m4 = (16 + g < rem) ? c5 : n;
        int m5 = (20 + g < rem) ? c6 : n;
        int m6 = (24 + g < rem) ? c7 : n;
        int m7 = (28 + g < rem) ? c8 : n;
        uint2 u0 = GR(c0), u1 = GR(c1), u2 = GR(c2), u3 = GR(c3);
        uint2 u4 = GR(m4), u5 = GR(m5), u6 = GR(m6), u7 = GR(m7);
        GACC(u0) GACC(u1) GACC(u2) GACC(u3)
        GACC(u4) GACC(u5) GACC(u6) GACC(u7)
    } else if (rem > 0) {
        int c0 = col[e + g],     c1 = col[e + 4 + g];
        int c2 = col[e + 8 + g], c3 = col[e + 12 + g];
        int m0 = (g < rem)      ? c0 : n;
        int m1 = (4 + g < rem)  ? c1 : n;
        int m2 = (8 + g < rem)  ? c2 : n;
        int m3 = (12 + g < rem) ? c3 : n;
        uint2 u0 = GR(m0), u1 = GR(m1), u2 = GR(m2), u3 = GR(m3);
        GACC(u0) GACC(u1) GACC(u2) GACC(u3)
    }
#undef GR
#undef GACC

    a0 += __shfl_xor(a0, 16); a0 += __shfl_xor(a0, 32);
    a1 += __shfl_xor(a1, 16); a1 += __shfl_xor(a1, 32);
    a2 += __shfl_xor(a2, 16); a2 += __shfl_xor(a2, 32);
    a3 += __shfl_xor(a3, 16); a3 += __shfl_xor(a3, 32);

    if (lane < 16) {
        a0 += bflo(us.x); a1 += bfhi(us.x);
        a2 += bflo(us.y); a3 += bfhi(us.y);
        float4 bv = *(const float4*)(bias + c4 * 4);
        float o0 = sc * a0 + bv.x, o1 = sc * a1 + bv.y;
        float o2 = sc * a2 + bv.z, o3 = sc * a3 + bv.w;
        if (RELU) {
            o0 = fmaxf(o0, 0.f); o1 = fmaxf(o1, 0.f);
            o2 = fmaxf(o2, 0.f); o3 = fmaxf(o3, 0.f);
        }
        if (F32OUT) {
            uint2 rb = *(const uint2*)(residb + (size_t)node * 64 + c4 * 4);
            o0 += bflo(rb.x); o1 += bfhi(rb.x);
            o2 += bflo(rb.y); o3 += bfhi(rb.y);
            *(float4*)(outf + (size_t)node * 64 + c4 * 4) =
                make_float4(o0, o1, o2, o3);
        } else {
            unsigned w0 = f2bf(o0) | (f2bf(o1) << 16);
            unsigned w1 = f2bf(o2) | (f2bf(o3) << 16);
            *(uint2*)(outb + (size_t)node * 64 + c4 * 4) = make_uint2(w0, w1);
        }
    }
}

// ---------------------------------------------------------------------------
extern "C" void kernel_launch(void* const* d_in, const int* in_sizes, int n_in,
                              void* d_out, int out_size, void* d_ws, size_t ws_size,
                              hipStream_t stream) {
    const float* x  = (const float*)d_in[0];
    const int*   ei = (const int*)d_in[1];
    const float* W0 = (const float*)d_in[2];
    const float* b0 = (const float*)d_in[3];
    const float* Ws = (const float*)d_in[4];
    const float* bs = (const float*)d_in[5];
    float* out = (float*)d_out;

    const int N = in_sizes[0] / 128;
    const int E = in_sizes[1] / 2;
    const int B = (N + BKN - 1) >> LB;

    char* p = (char*)d_ws;
    auto carve = [&](size_t bytes) {
        char* r = p;
        p += (bytes + 255) & ~(size_t)255;
        return r;
    };
    int*      bucketCursor = (int*)carve(512 * 4);
    unsigned* packed       = (unsigned*)carve((size_t)B * CAP * 4);
    int*      col          = (int*)carve(((size_t)B * CAPCOL + 64) * 4);  // +guard
    int2*     rp2          = (int2*)carve((size_t)N * 8);
    float*    dinv         = (float*)carve((size_t)N * 4);
    ushort_t* hs           = (ushort_t*)carve((size_t)(N + 1) * 64 * 2); // +sentinel
    ushort_t* xtb          = (ushort_t*)carve((size_t)N * 64 * 2);
    ushort_t* hb           = (ushort_t*)carve((size_t)N * 64 * 2);

    hipMemsetAsync(bucketCursor, 0, 512 * 4, stream);

    k_scatter<<<(E + CHUNK - 1) / CHUNK, 256, 0, stream>>>(ei, E, bucketCursor, packed);
    k_sort<<<B, 256, 0, stream>>>(packed, bucketCursor, col, rp2, dinv, hs, N);

    int gb = (N + 127) / 128;
    int ablocks = (N + 3) / 4;   // 1 node/wave, 4 waves/block

    // layer 1: hs = (x @ W0) * dinv ; agg1 -> xtb (bf16, +b0, no relu)
    k_gemm1<<<gb, 256, 0, stream>>>(x, W0, dinv, hs, N);
    k_aggb<0, 0><<<ablocks, 256, 0, stream>>>(hs, dinv, b0, col, rp2,
                                              nullptr, nullptr, xtb, N);
    // layer 2: hs = (xtb @ Ws0) * dinv ; agg2 -> hb (bf16, +bs0, relu)
    k_gemm64<<<gb, 256, 0, stream>>>(xtb, Ws, dinv, hs, N);
    k_aggb<1, 0><<<ablocks, 256, 0, stream>>>(hs, dinv, bs, col, rp2,
                                              nullptr, nullptr, hb, N);
    // layer 3: hs = (hb @ Ws1) * dinv ; agg3 -> out (f32, +bs1, relu, +resid)
    k_gemm64<<<gb, 256, 0, stream>>>(hb, Ws + 64 * 64, dinv, hs, N);
    k_aggb<1, 1><<<ablocks, 256, 0, stream>>>(hs, dinv, bs + 64, col, rp2,
                                              xtb, out, nullptr, N);
}